// Round 1
// baseline (64.792 us; speedup 1.0000x reference)
//
#include <hip/hip_runtime.h>

// YOLO decode: (32, 3*85, 64, 64) f32 -> (32, 3*64*64, 85) f32
// attr transpose + sigmoid/exp elementwise. Memory-bound.

#define NB   32          // batch
#define NA   3           // anchors
#define ATTRS 85         // 5 + 80 classes
#define HH   64
#define WW   64
#define HWSZ (HH * WW)   // 4096
#define TP   128         // hw-positions per block tile
#define NTILES (HWSZ / TP) // 32
#define PITCH 129        // odd pitch -> bank-conflict-light transposed reads

__global__ __launch_bounds__(256)
void yolo_decode_kernel(const float* __restrict__ in,
                        const float* __restrict__ anchors,
                        const int* __restrict__ imh,
                        const int* __restrict__ imw,
                        float* __restrict__ out)
{
    __shared__ float lds[ATTRS * PITCH];

    const int bid  = blockIdx.x;
    const int tile = bid % NTILES;
    const int ba   = bid / NTILES;
    const int a    = ba % NA;
    const int b    = ba / NA;
    const int pos0 = tile * TP;
    const int tid  = threadIdx.x;

    const float stride_w = (float)(*imw) / (float)WW;
    const float stride_h = (float)(*imh) / (float)HH;
    const float aw = anchors[a * 2 + 0];
    const float ah = anchors[a * 2 + 1];

    const float* __restrict__ src =
        in + (size_t)(b * (NA * ATTRS) + a * ATTRS) * HWSZ + pos0;

    // ---- load + transform: coalesced float4 along hw, stage transposed-ready in LDS
    // ATTRS * (TP/4) = 85 * 32 = 2720 float4 chunks
    for (int idx = tid; idx < ATTRS * (TP / 4); idx += 256) {
        const int attr = idx >> 5;   // TP/4 == 32
        const int p4   = idx & 31;
        const float4 v = *(const float4*)(src + (size_t)attr * HWSZ + p4 * 4);
        float vals[4] = {v.x, v.y, v.z, v.w};
#pragma unroll
        for (int j = 0; j < 4; ++j) {
            const int pos = pos0 + p4 * 4 + j;  // global hw index 0..4095
            const float x = vals[j];
            float r;
            if (attr == 0) {
                const float s = 1.0f / (1.0f + __expf(-x));
                r = (s + (float)(pos & (WW - 1))) * stride_w;
            } else if (attr == 1) {
                const float s = 1.0f / (1.0f + __expf(-x));
                r = (s + (float)(pos >> 6)) * stride_h;
            } else if (attr == 2) {
                r = __expf(x) * aw;
            } else if (attr == 3) {
                r = __expf(x) * ah;
            } else {
                r = 1.0f / (1.0f + __expf(-x));
            }
            lds[attr * PITCH + p4 * 4 + j] = r;
        }
    }
    __syncthreads();

    // ---- store: output tile is one contiguous span of TP*ATTRS = 10880 floats
    float* __restrict__ dst =
        out + ((size_t)(b * NA + a) * HWSZ + pos0) * ATTRS;
    for (int idx = tid; idx < (TP * ATTRS) / 4; idx += 256) {
        const int f0 = idx * 4;
        float tmp[4];
#pragma unroll
        for (int j = 0; j < 4; ++j) {
            const unsigned f    = (unsigned)(f0 + j);
            const unsigned pos  = f / 85u;           // magic-multiply
            const unsigned attr = f - pos * 85u;
            tmp[j] = lds[attr * PITCH + pos];
        }
        float4 v;
        v.x = tmp[0]; v.y = tmp[1]; v.z = tmp[2]; v.w = tmp[3];
        *(float4*)(dst + f0) = v;
    }
}

extern "C" void kernel_launch(void* const* d_in, const int* in_sizes, int n_in,
                              void* d_out, int out_size, void* d_ws, size_t ws_size,
                              hipStream_t stream) {
    const float* in      = (const float*)d_in[0];
    const float* anchors = (const float*)d_in[1];
    const int*   imh     = (const int*)d_in[2];
    const int*   imw     = (const int*)d_in[3];
    float* out = (float*)d_out;

    const int nblocks = NB * NA * NTILES;  // 3072
    yolo_decode_kernel<<<nblocks, 256, 0, stream>>>(in, anchors, imh, imw, out);
}

// Round 2
// 46.384 us; speedup vs baseline: 1.3969x; 1.3969x over previous
//
#include <hip/hip_runtime.h>

// YOLO decode: (32, 3*85, 64, 64) f32 -> (32, 3*64*64, 85) f32
// Wave-private LDS transpose in output layout; no block barrier.

#define NB    32
#define NA    3
#define ATTRS 85
#define HH    64
#define WW    64
#define HWSZ  (HH * WW)        // 4096
#define TPW   16               // positions per wave-tile
#define TILES_PER_BA (HWSZ / TPW)   // 256
#define CHUNKS (ATTRS * (TPW / 4))  // 340 float4 chunks per tile
#define WAVE_LDS (TPW * ATTRS)      // 1360 floats per wave

__global__ __launch_bounds__(256)
void yolo_decode_kernel(const float* __restrict__ in,
                        const float* __restrict__ anchors,
                        const int* __restrict__ imh,
                        const int* __restrict__ imw,
                        float* __restrict__ out)
{
    __shared__ float lds[4 * WAVE_LDS];   // 21760 B -> 7 blocks/CU

    const int tid  = threadIdx.x;
    const int wid  = tid >> 6;
    const int lane = tid & 63;
    float* __restrict__ wlds = lds + wid * WAVE_LDS;

    const int wtile = blockIdx.x * 4 + wid;      // 0 .. 24575
    const int tile  = wtile & (TILES_PER_BA - 1);
    const int ba    = wtile >> 8;                // b*3 + a
    const int b     = ba / NA;
    const int a     = ba - b * NA;
    const int pos0  = tile * TPW;

    const float stride_w = (float)(*imw) / (float)WW;
    const float stride_h = (float)(*imh) / (float)HH;
    const float aw = anchors[a * 2 + 0];
    const float ah = anchors[a * 2 + 1];

    // tile never crosses a grid row (pos0 % 64 in {0,16,32,48})
    const float gy  = (float)(pos0 >> 6);
    const int   gx0 = pos0 & (WW - 1);

    const float* __restrict__ src =
        in + (size_t)(b * (NA * ATTRS) + a * ATTRS) * HWSZ + pos0;

    // ---- load + transform + scatter into output-layout LDS
    for (int i = lane; i < CHUNKS; i += 64) {
        const int attr = i >> 2;      // 0..84
        const int p4   = i & 3;       // which float4 within the 16-pos row
        const float4 v = *(const float4*)(src + (size_t)attr * HWSZ + p4 * 4);
        float x[4] = {v.x, v.y, v.z, v.w};
        float r[4];
        if (attr >= 4) {              // conf + classes: sigmoid
#pragma unroll
            for (int j = 0; j < 4; ++j)
                r[j] = 1.0f / (1.0f + __expf(-x[j]));
        } else if (attr == 0) {       // box x
#pragma unroll
            for (int j = 0; j < 4; ++j) {
                const float s = 1.0f / (1.0f + __expf(-x[j]));
                r[j] = (s + (float)(gx0 + p4 * 4 + j)) * stride_w;
            }
        } else if (attr == 1) {       // box y
#pragma unroll
            for (int j = 0; j < 4; ++j) {
                const float s = 1.0f / (1.0f + __expf(-x[j]));
                r[j] = (s + gy) * stride_h;
            }
        } else if (attr == 2) {       // box w
#pragma unroll
            for (int j = 0; j < 4; ++j)
                r[j] = __expf(x[j]) * aw;
        } else {                      // attr == 3: box h
#pragma unroll
            for (int j = 0; j < 4; ++j)
                r[j] = __expf(x[j]) * ah;
        }
#pragma unroll
        for (int j = 0; j < 4; ++j)
            wlds[(p4 * 4 + j) * ATTRS + attr] = r[j];
    }

    // ---- intra-wave only: compiler orders ds_write -> ds_read via lgkmcnt.
    // LDS holds the tile in exact output order -> pure vectorized copy out.
    float* __restrict__ dst =
        out + ((size_t)ba * HWSZ + pos0) * ATTRS;
    for (int i = lane; i < CHUNKS; i += 64) {
        const float4 v = *(const float4*)(wlds + i * 4);
        *(float4*)(dst + i * 4) = v;
    }
}

extern "C" void kernel_launch(void* const* d_in, const int* in_sizes, int n_in,
                              void* d_out, int out_size, void* d_ws, size_t ws_size,
                              hipStream_t stream) {
    const float* in      = (const float*)d_in[0];
    const float* anchors = (const float*)d_in[1];
    const int*   imh     = (const int*)d_in[2];
    const int*   imw     = (const int*)d_in[3];
    float* out = (float*)d_out;

    const int nwaves  = NB * NA * TILES_PER_BA;  // 24576
    const int nblocks = nwaves / 4;              // 6144
    yolo_decode_kernel<<<nblocks, 256, 0, stream>>>(in, anchors, imh, imw, out);
}

// Round 4
// 44.869 us; speedup vs baseline: 1.4440x; 1.0338x over previous
//
#include <hip/hip_runtime.h>

// YOLO decode: (32, 3*85, 64, 64) f32 -> (32, 3*64*64, 85) f32
// Wave-private LDS transpose in output layout; no block barrier.
// Non-temporal output stores keep the input L3-resident across replays.

#define NB    32
#define NA    3
#define ATTRS 85
#define HH    64
#define WW    64
#define HWSZ  (HH * WW)        // 4096
#define TPW   16               // positions per wave-tile
#define TILES_PER_BA (HWSZ / TPW)   // 256
#define CHUNKS (ATTRS * (TPW / 4))  // 340 float4 chunks per tile
#define WAVE_LDS (TPW * ATTRS)      // 1360 floats per wave

typedef float f32x4 __attribute__((ext_vector_type(4)));  // native vector: OK for nontemporal builtin

__device__ __forceinline__ float fast_sigmoid(float x) {
    // v_rcp_f32 instead of the full IEEE divide sequence (~1 ulp, fine here)
    return __builtin_amdgcn_rcpf(1.0f + __expf(-x));
}

__global__ __launch_bounds__(256)
void yolo_decode_kernel(const float* __restrict__ in,
                        const float* __restrict__ anchors,
                        const int* __restrict__ imh,
                        const int* __restrict__ imw,
                        float* __restrict__ out)
{
    __shared__ float lds[4 * WAVE_LDS];   // 21760 B -> 7 blocks/CU

    const int tid  = threadIdx.x;
    const int wid  = tid >> 6;
    const int lane = tid & 63;
    float* __restrict__ wlds = lds + wid * WAVE_LDS;

    const int wtile = blockIdx.x * 4 + wid;      // 0 .. 24575
    const int tile  = wtile & (TILES_PER_BA - 1);
    const int ba    = wtile >> 8;                // b*3 + a
    const int b     = ba / NA;
    const int a     = ba - b * NA;
    const int pos0  = tile * TPW;

    const float stride_w = (float)(*imw) / (float)WW;
    const float stride_h = (float)(*imh) / (float)HH;
    const float aw = anchors[a * 2 + 0];
    const float ah = anchors[a * 2 + 1];

    // tile never crosses a grid row (pos0 % 64 in {0,16,32,48})
    const float gy  = (float)(pos0 >> 6);
    const int   gx0 = pos0 & (WW - 1);

    const float* __restrict__ src =
        in + (size_t)(b * (NA * ATTRS) + a * ATTRS) * HWSZ + pos0;

    // ---- load + transform + scatter into output-layout LDS
#pragma unroll
    for (int i = lane; i < CHUNKS; i += 64) {
        const int attr = i >> 2;      // 0..84
        const int p4   = i & 3;       // which float4 within the 16-pos row
        const f32x4 v = *(const f32x4*)(src + (size_t)attr * HWSZ + p4 * 4);
        float x[4] = {v.x, v.y, v.z, v.w};
        float r[4];
        if (attr >= 4) {              // conf + classes: sigmoid
#pragma unroll
            for (int j = 0; j < 4; ++j)
                r[j] = fast_sigmoid(x[j]);
        } else if (attr == 0) {       // box x
#pragma unroll
            for (int j = 0; j < 4; ++j)
                r[j] = (fast_sigmoid(x[j]) + (float)(gx0 + p4 * 4 + j)) * stride_w;
        } else if (attr == 1) {       // box y
#pragma unroll
            for (int j = 0; j < 4; ++j)
                r[j] = (fast_sigmoid(x[j]) + gy) * stride_h;
        } else if (attr == 2) {       // box w
#pragma unroll
            for (int j = 0; j < 4; ++j)
                r[j] = __expf(x[j]) * aw;
        } else {                      // attr == 3: box h
#pragma unroll
            for (int j = 0; j < 4; ++j)
                r[j] = __expf(x[j]) * ah;
        }
#pragma unroll
        for (int j = 0; j < 4; ++j)
            wlds[(p4 * 4 + j) * ATTRS + attr] = r[j];
    }

    // ---- intra-wave only: compiler orders ds_write -> ds_read via lgkmcnt.
    // LDS holds the tile in exact output order -> pure vectorized copy out.
    // Non-temporal stores: don't let the streaming output evict the input
    // from Infinity Cache.
    float* __restrict__ dst =
        out + ((size_t)ba * HWSZ + pos0) * ATTRS;
#pragma unroll
    for (int i = lane; i < CHUNKS; i += 64) {
        const f32x4 v = *(const f32x4*)(wlds + i * 4);
        __builtin_nontemporal_store(v, (f32x4*)(dst + i * 4));
    }
}

extern "C" void kernel_launch(void* const* d_in, const int* in_sizes, int n_in,
                              void* d_out, int out_size, void* d_ws, size_t ws_size,
                              hipStream_t stream) {
    const float* in      = (const float*)d_in[0];
    const float* anchors = (const float*)d_in[1];
    const int*   imh     = (const int*)d_in[2];
    const int*   imw     = (const int*)d_in[3];
    float* out = (float*)d_out;

    const int nwaves  = NB * NA * TILES_PER_BA;  // 24576
    const int nblocks = nwaves / 4;              // 6144
    yolo_decode_kernel<<<nblocks, 256, 0, stream>>>(in, anchors, imh, imw, out);
}

// Round 5
// 44.414 us; speedup vs baseline: 1.4588x; 1.0102x over previous
//
#include <hip/hip_runtime.h>

// YOLO decode: (32, 3*85, 64, 64) f32 -> (32, 3*64*64, 85) f32
// Wave-private LDS transpose in output layout; no block barrier.
// Inline-asm streaming stores (sc0 sc1 nt) attempt to keep the output
// stream out of Infinity Cache so the input stays L3-resident.

#define NB    32
#define NA    3
#define ATTRS 85
#define HH    64
#define WW    64
#define HWSZ  (HH * WW)        // 4096
#define TPW   16               // positions per wave-tile
#define TILES_PER_BA (HWSZ / TPW)   // 256
#define CHUNKS (ATTRS * (TPW / 4))  // 340 float4 chunks per tile
#define WAVE_LDS (TPW * ATTRS)      // 1360 floats per wave

typedef float f32x4 __attribute__((ext_vector_type(4)));

__device__ __forceinline__ float fast_sigmoid(float x) {
    // v_rcp_f32 instead of the full IEEE divide sequence (~1 ulp, fine here)
    return __builtin_amdgcn_rcpf(1.0f + __expf(-x));
}

__device__ __forceinline__ void stream_store4(float* p, f32x4 v) {
    // system-scope + non-temporal: strongest cache-bypass hint on gfx950
    asm volatile("global_store_dwordx4 %0, %1, off sc0 sc1 nt"
                 :: "v"(p), "v"(v));
}

__global__ __launch_bounds__(256)
void yolo_decode_kernel(const float* __restrict__ in,
                        const float* __restrict__ anchors,
                        const int* __restrict__ imh,
                        const int* __restrict__ imw,
                        float* __restrict__ out)
{
    __shared__ float lds[4 * WAVE_LDS];   // 21760 B -> 7 blocks/CU

    const int tid  = threadIdx.x;
    const int wid  = tid >> 6;
    const int lane = tid & 63;
    float* __restrict__ wlds = lds + wid * WAVE_LDS;

    const int wtile = blockIdx.x * 4 + wid;      // 0 .. 24575
    const int tile  = wtile & (TILES_PER_BA - 1);
    const int ba    = wtile >> 8;                // b*3 + a
    const int b     = ba / NA;
    const int a     = ba - b * NA;
    const int pos0  = tile * TPW;

    const float stride_w = (float)(*imw) / (float)WW;
    const float stride_h = (float)(*imh) / (float)HH;
    const float aw = anchors[a * 2 + 0];
    const float ah = anchors[a * 2 + 1];

    // tile never crosses a grid row (pos0 % 64 in {0,16,32,48})
    const float gy  = (float)(pos0 >> 6);
    const int   gx0 = pos0 & (WW - 1);

    const float* __restrict__ src =
        in + (size_t)(b * (NA * ATTRS) + a * ATTRS) * HWSZ + pos0;

    // ---- load + transform + scatter into output-layout LDS
#pragma unroll
    for (int i = lane; i < CHUNKS; i += 64) {
        const int attr = i >> 2;      // 0..84
        const int p4   = i & 3;       // which float4 within the 16-pos row
        const f32x4 v = *(const f32x4*)(src + (size_t)attr * HWSZ + p4 * 4);
        float x[4] = {v.x, v.y, v.z, v.w};
        float r[4];
        if (attr >= 4) {              // conf + classes: sigmoid
#pragma unroll
            for (int j = 0; j < 4; ++j)
                r[j] = fast_sigmoid(x[j]);
        } else if (attr == 0) {       // box x
#pragma unroll
            for (int j = 0; j < 4; ++j)
                r[j] = (fast_sigmoid(x[j]) + (float)(gx0 + p4 * 4 + j)) * stride_w;
        } else if (attr == 1) {       // box y
#pragma unroll
            for (int j = 0; j < 4; ++j)
                r[j] = (fast_sigmoid(x[j]) + gy) * stride_h;
        } else if (attr == 2) {       // box w
#pragma unroll
            for (int j = 0; j < 4; ++j)
                r[j] = __expf(x[j]) * aw;
        } else {                      // attr == 3: box h
#pragma unroll
            for (int j = 0; j < 4; ++j)
                r[j] = __expf(x[j]) * ah;
        }
#pragma unroll
        for (int j = 0; j < 4; ++j)
            wlds[(p4 * 4 + j) * ATTRS + attr] = r[j];
    }

    // ---- intra-wave only: compiler orders ds_write -> ds_read via lgkmcnt.
    // LDS holds the tile in exact output order -> pure vectorized copy out.
    float* __restrict__ dst =
        out + ((size_t)ba * HWSZ + pos0) * ATTRS;
#pragma unroll
    for (int i = lane; i < CHUNKS; i += 64) {
        const f32x4 v = *(const f32x4*)(wlds + i * 4);
        stream_store4(dst + i * 4, v);
    }
}

extern "C" void kernel_launch(void* const* d_in, const int* in_sizes, int n_in,
                              void* d_out, int out_size, void* d_ws, size_t ws_size,
                              hipStream_t stream) {
    const float* in      = (const float*)d_in[0];
    const float* anchors = (const float*)d_in[1];
    const int*   imh     = (const int*)d_in[2];
    const int*   imw     = (const int*)d_in[3];
    float* out = (float*)d_out;

    const int nwaves  = NB * NA * TILES_PER_BA;  // 24576
    const int nblocks = nwaves / 4;              // 6144
    yolo_decode_kernel<<<nblocks, 256, 0, stream>>>(in, anchors, imh, imw, out);
}